// Round 1
// baseline (319.300 us; speedup 1.0000x reference)
//
#include <hip/hip_runtime.h>

// MultiRelationalSelfAttention: B=4,H=16,N=1024,D=64,T=4
//   S = Q@K^T * (1 + sum_t w[t,h]*A[t,b]) / 8 ; W = softmax(S); out = W@V
// Outputs (concat): out [B,H,N,D] f32, then attn_weight [B,H,N,N] f32.
//
// Round 0: fused per (b,h,16-row block). bf16 MFMA with hi/lo split on Q,K
// for precision; scores in 64KB LDS (XOR-swizzled); wave-parallel softmax;
// PV with V read directly from global. LDS = 80KB exactly -> 2 blocks/CU.

#define NB 4
#define NH 16
#define NN 1024
#define ND 64
#define NT 4

typedef short s16x4 __attribute__((ext_vector_type(4)));
typedef short s16x8 __attribute__((ext_vector_type(8)));
typedef float f32x4 __attribute__((ext_vector_type(4)));

__device__ __forceinline__ short f2bf(float f) {
  return __builtin_bit_cast(short, (__bf16)f);
}
__device__ __forceinline__ float bf2f(short s) {
  return __builtin_bit_cast(float, ((unsigned)(unsigned short)s) << 16);
}

__global__ __launch_bounds__(256, 2) void mrsa_fused(
    const float* __restrict__ Qg, const float* __restrict__ Kg,
    const float* __restrict__ Vg, const float* __restrict__ Ag,
    const float* __restrict__ Wg, float* __restrict__ outO,
    float* __restrict__ outW) {
  // LDS: K chunk (64 cols x 64 k) hi/lo bf16 + score tile 16x1024 f32 = 80KB
  __shared__ short KsHi[64 * 64];
  __shared__ short KsLo[64 * 64];
  __shared__ float Ss[16 * 1024];

  const int tid = threadIdx.x;
  const int lane = tid & 63;
  const int wv = tid >> 6;
  const int rb = blockIdx.x;  // 0..63 row block
  const int h = blockIdx.y;
  const int b = blockIdx.z;
  const int row0 = rb * 16;

  const size_t bh = (size_t)b * NH + h;
  const float* Qp = Qg + bh * (NN * ND);
  const float* Kp = Kg + bh * (NN * ND);
  const float* Vp = Vg + bh * (NN * ND);

  float wE[NT];
#pragma unroll
  for (int t = 0; t < NT; ++t) wE[t] = Wg[t * NH + h];

  const int arow = lane & 15;        // A-frag row (out row of MFMA tile)
  const int k0 = (lane >> 4) * 8;    // A/B-frag k base within 32

  // ---- Q fragments (hi/lo bf16 split) held in registers for all chunks ----
  s16x8 qh[2], ql[2];
#pragma unroll
  for (int ks = 0; ks < 2; ++ks) {
    const float* qrow = Qp + (size_t)(row0 + arow) * ND + ks * 32 + k0;
#pragma unroll
    for (int j = 0; j < 8; ++j) {
      float f = qrow[j];
      short hi = f2bf(f);
      qh[ks][j] = hi;
      ql[ks][j] = f2bf(f - bf2f(hi));
    }
  }

  const int bcol = wv * 16 + (lane & 15);  // B-frag col within 64-col chunk
  const int bsw = (bcol & 7) << 3;         // K LDS xor-swizzle for this col

  // =================== Phase 1: S = QK^T * (1+bias)/8 ====================
  for (int c = 0; c < 16; ++c) {
    // stage K rows c*64..c*64+63 (these are score columns), hi/lo bf16
#pragma unroll
    for (int i = 0; i < 4; ++i) {
      int e4 = tid + i * 256;    // 1024 float4s = 64 rows x 16 quads
      int r = e4 >> 4;           // K row within chunk (= score col)
      int d0 = (e4 & 15) * 4;    // k position
      float4 kv = *reinterpret_cast<const float4*>(
          Kp + (size_t)(c * 64 + r) * ND + d0);
      float kf[4];
      kf[0] = kv.x; kf[1] = kv.y; kf[2] = kv.z; kf[3] = kv.w;
      s16x4 hi4, lo4;
#pragma unroll
      for (int j = 0; j < 4; ++j) {
        short hi = f2bf(kf[j]);
        hi4[j] = hi;
        lo4[j] = f2bf(kf[j] - bf2f(hi));
      }
      int sw = r * 64 + (d0 ^ ((r & 7) << 3));  // xor-swizzle bits 3..5
      *reinterpret_cast<s16x4*>(&KsHi[sw]) = hi4;
      *reinterpret_cast<s16x4*>(&KsLo[sw]) = lo4;
    }
    __syncthreads();

    f32x4 acc = {0.f, 0.f, 0.f, 0.f};
#pragma unroll
    for (int ks = 0; ks < 2; ++ks) {
      int kb = ks * 32 + k0;
      int ph = bcol * 64 + (kb ^ bsw);
      s16x8 kh8 = *reinterpret_cast<const s16x8*>(&KsHi[ph]);
      s16x8 kl8 = *reinterpret_cast<const s16x8*>(&KsLo[ph]);
      acc = __builtin_amdgcn_mfma_f32_16x16x32_bf16(qh[ks], kh8, acc, 0, 0, 0);
      acc = __builtin_amdgcn_mfma_f32_16x16x32_bf16(qh[ks], kl8, acc, 0, 0, 0);
      acc = __builtin_amdgcn_mfma_f32_16x16x32_bf16(ql[ks], kh8, acc, 0, 0, 0);
    }

    // bias from A, scale, store to swizzled Ss
    int gcol = c * 64 + bcol;
#pragma unroll
    for (int r = 0; r < 4; ++r) {
      int lrow = (lane >> 4) * 4 + r;  // C/D: col=lane&15, row=(lane>>4)*4+r
      int grow = row0 + lrow;
      float bias = 0.f;
#pragma unroll
      for (int t = 0; t < NT; ++t)
        bias += wE[t] *
                Ag[((size_t)t * NB + b) * (NN * NN) + (size_t)grow * NN + gcol];
      Ss[lrow * 1024 + (gcol ^ ((lrow & 7) << 3))] =
          acc[r] * (1.f + bias) * 0.125f;
    }
    __syncthreads();
  }

  // =================== Phase 2: row softmax + weight write ================
  // wave wv handles rows wv*4 .. wv*4+3; Ss cols are xor-permuted (bijective,
  // max/sum are permutation-invariant; global write un-permutes).
#pragma unroll
  for (int rr = 0; rr < 4; ++rr) {
    int lrow = wv * 4 + rr;
    float* srow = &Ss[lrow * 1024];
    int sw = (lrow & 7) << 3;
    float m = -3.4e38f;
#pragma unroll
    for (int i = 0; i < 16; ++i) m = fmaxf(m, srow[i * 64 + lane]);
#pragma unroll
    for (int off = 32; off; off >>= 1) m = fmaxf(m, __shfl_xor(m, off));
    float ev[16];
    float lsum = 0.f;
#pragma unroll
    for (int i = 0; i < 16; ++i) {
      float e = __expf(srow[i * 64 + lane] - m);
      ev[i] = e;
      lsum += e;
    }
#pragma unroll
    for (int off = 32; off; off >>= 1) lsum += __shfl_xor(lsum, off);
    float inv = 1.f / lsum;
    float* gw = outW + (bh * NN + (size_t)(row0 + lrow)) * NN;
#pragma unroll
    for (int i = 0; i < 16; ++i) {
      float w = ev[i] * inv;
      int p = i * 64 + lane;
      srow[p] = w;          // normalized weights kept for PV
      gw[p ^ sw] = w;       // un-permute; still fully coalesced per 256B seg
    }
  }
  __syncthreads();

  // =================== Phase 3: out = W @ V ==============================
  {
    f32x4 acc = {0.f, 0.f, 0.f, 0.f};
    const int dcol = wv * 16 + (lane & 15);  // output d column
    const int asw = (arow & 7) << 3;
    const float* srow = &Ss[arow * 1024];
#pragma unroll 2
    for (int kk = 0; kk < 32; ++kk) {
      int kb = kk * 32 + k0;
      int ph = kb ^ asw;  // 8-aligned -> contiguous 8 floats
      float4 a0 = *reinterpret_cast<const float4*>(&srow[ph]);
      float4 a1 = *reinterpret_cast<const float4*>(&srow[ph + 4]);
      s16x8 af, bf;
      af[0] = f2bf(a0.x); af[1] = f2bf(a0.y);
      af[2] = f2bf(a0.z); af[3] = f2bf(a0.w);
      af[4] = f2bf(a1.x); af[5] = f2bf(a1.y);
      af[6] = f2bf(a1.z); af[7] = f2bf(a1.w);
      const float* vcol = Vp + (size_t)kb * ND + dcol;
#pragma unroll
      for (int j = 0; j < 8; ++j) bf[j] = f2bf(vcol[j * ND]);
      acc = __builtin_amdgcn_mfma_f32_16x16x32_bf16(af, bf, acc, 0, 0, 0);
    }
#pragma unroll
    for (int r = 0; r < 4; ++r) {
      int lrow = (lane >> 4) * 4 + r;
      outO[(bh * NN + (size_t)(row0 + lrow)) * ND + dcol] = acc[r];
    }
  }
}

extern "C" void kernel_launch(void* const* d_in, const int* in_sizes, int n_in,
                              void* d_out, int out_size, void* d_ws,
                              size_t ws_size, hipStream_t stream) {
  const float* Q = (const float*)d_in[0];
  const float* K = (const float*)d_in[1];
  const float* V = (const float*)d_in[2];
  const float* A = (const float*)d_in[3];
  const float* wE = (const float*)d_in[4];
  float* out = (float*)d_out;
  float* outW = out + (size_t)NB * NH * NN * ND;
  dim3 grid(NN / 16, NH, NB);
  hipLaunchKernelGGL(mrsa_fused, grid, dim3(256), 0, stream, Q, K, V, A, wE,
                     out, outW);
}